// Round 1
// baseline (24384.949 us; speedup 1.0000x reference)
//
#include <hip/hip_runtime.h>
#include <hip/hip_bf16.h>

#define Tseq 128
#define Din  63
#define G3   384
#define RPB  16
#define NTHR 512

// Pack weight matrix [384][Ks] -> packed [(g0, k4, i, kk)] with g = g0 + 32*i,
// k = 4*k4 + kk, dst K padded to Kd (zeros beyond Ks). This makes each thread's
// 12 float4 loads per k-step contiguous (192 B run) -> immediate-offset loads.
__global__ void pack_w(const float* __restrict__ src, float* __restrict__ dst,
                       int Kd, int Ks) {
  int idx = blockIdx.x * blockDim.x + threadIdx.x;
  if (idx >= 384 * Kd) return;
  int kk = idx & 3;
  int rest = idx >> 2;
  int i = rest % 12;
  rest /= 12;
  int k4 = rest % (Kd / 4);
  int g0 = rest / (Kd / 4);
  int g = g0 + 32 * i;
  int k = k4 * 4 + kk;
  dst[idx] = (k < Ks) ? src[g * Ks + k] : 0.0f;
}

__global__ __launch_bounds__(NTHR, 2) void gru_fused(
    const float* __restrict__ x,
    const float* __restrict__ wih0p, const float* __restrict__ whh0p,
    const float* __restrict__ wih1p, const float* __restrict__ whh1p,
    const float* __restrict__ bih0, const float* __restrict__ bhh0,
    const float* __restrict__ bih1, const float* __restrict__ bhh1,
    const float* __restrict__ w1, const float* __restrict__ b1,
    const float* __restrict__ w2, const float* __restrict__ b2,
    float* __restrict__ out)
{
  // Padded strides: 132*4=528B and 68*4=272B are 16B-aligned (b128 ok) and the
  // dword4-group index is odd -> conflict-free across the 16 r-lanes.
  __shared__ float h0s[RPB][132];
  __shared__ float h1s[RPB][132];
  __shared__ float xs[RPB][68];
  __shared__ float bias[4][G3];
  __shared__ float hid[RPB][68];

  const int tid = threadIdx.x;
  const int r   = tid & 15;
  const int g0  = tid >> 4;           // 0..31
  const long b0 = (long)blockIdx.x * RPB;

  for (int i = tid; i < G3; i += NTHR) {
    bias[0][i] = bih0[i]; bias[1][i] = bhh0[i];
    bias[2][i] = bih1[i]; bias[3][i] = bhh1[i];
  }
  for (int i = tid; i < RPB * 132; i += NTHR) { (&h0s[0][0])[i] = 0.f; (&h1s[0][0])[i] = 0.f; }
  for (int i = tid; i < RPB * 68; i += NTHR) (&xs[0][0])[i] = 0.f;
  __syncthreads();

  for (int t = 0; t < Tseq; ++t) {
    // ---- stage x[t] for this block's 16 rows ----
    for (int i = tid; i < RPB * Din; i += NTHR) {
      int rr = i / Din, k = i - rr * Din;
      xs[rr][k] = x[((b0 + rr) * Tseq + t) * Din + k];
    }
    __syncthreads();

    float accx[12], acch[12];
    #pragma unroll
    for (int i = 0; i < 12; ++i) { accx[i] = 0.f; acch[i] = 0.f; }

    // ---- layer0: x-part (K padded to 64) ----
    {
      const float* wp = wih0p + (size_t)(g0 * 16) * 48;
      for (int k4 = 0; k4 < 16; ++k4, wp += 48) {
        float4 av = *(const float4*)&xs[r][k4 * 4];
        #pragma unroll
        for (int i = 0; i < 12; ++i) {
          float4 wv = ((const float4*)wp)[i];
          accx[i] = fmaf(wv.x, av.x, fmaf(wv.y, av.y, fmaf(wv.z, av.z, fmaf(wv.w, av.w, accx[i]))));
        }
      }
    }
    // ---- layer0: h-part (K=128) ----
    {
      const float* wp = whh0p + (size_t)(g0 * 32) * 48;
      for (int k4 = 0; k4 < 32; ++k4, wp += 48) {
        float4 av = *(const float4*)&h0s[r][k4 * 4];
        #pragma unroll
        for (int i = 0; i < 12; ++i) {
          float4 wv = ((const float4*)wp)[i];
          acch[i] = fmaf(wv.x, av.x, fmaf(wv.y, av.y, fmaf(wv.z, av.z, fmaf(wv.w, av.w, acch[i]))));
        }
      }
    }
    __syncthreads();
    // ---- layer0 pointwise update: thread owns (r,z,n) of units j = g0+32m ----
    #pragma unroll
    for (int m = 0; m < 4; ++m) {
      int j = g0 + 32 * m;
      float pre_r = accx[m]     + bias[0][j]       + acch[m]     + bias[1][j];
      float pre_z = accx[m + 4] + bias[0][j + 128] + acch[m + 4] + bias[1][j + 128];
      float xn    = accx[m + 8] + bias[0][j + 256];
      float hn    = acch[m + 8] + bias[1][j + 256];
      float rg = 1.f / (1.f + __expf(-pre_r));
      float zg = 1.f / (1.f + __expf(-pre_z));
      float a2 = xn + rg * hn;
      float e2 = __expf(2.f * a2);
      float ng = (e2 - 1.f) / (e2 + 1.f);
      h0s[r][j] = (1.f - zg) * ng + zg * h0s[r][j];
    }
    __syncthreads();

    // ---- layer1: x-part = h0s (K=128), h-part = h1s (K=128) ----
    #pragma unroll
    for (int i = 0; i < 12; ++i) { accx[i] = 0.f; acch[i] = 0.f; }
    {
      const float* wp = wih1p + (size_t)(g0 * 32) * 48;
      for (int k4 = 0; k4 < 32; ++k4, wp += 48) {
        float4 av = *(const float4*)&h0s[r][k4 * 4];
        #pragma unroll
        for (int i = 0; i < 12; ++i) {
          float4 wv = ((const float4*)wp)[i];
          accx[i] = fmaf(wv.x, av.x, fmaf(wv.y, av.y, fmaf(wv.z, av.z, fmaf(wv.w, av.w, accx[i]))));
        }
      }
    }
    {
      const float* wp = whh1p + (size_t)(g0 * 32) * 48;
      for (int k4 = 0; k4 < 32; ++k4, wp += 48) {
        float4 av = *(const float4*)&h1s[r][k4 * 4];
        #pragma unroll
        for (int i = 0; i < 12; ++i) {
          float4 wv = ((const float4*)wp)[i];
          acch[i] = fmaf(wv.x, av.x, fmaf(wv.y, av.y, fmaf(wv.z, av.z, fmaf(wv.w, av.w, acch[i]))));
        }
      }
    }
    __syncthreads();
    #pragma unroll
    for (int m = 0; m < 4; ++m) {
      int j = g0 + 32 * m;
      float pre_r = accx[m]     + bias[2][j]       + acch[m]     + bias[3][j];
      float pre_z = accx[m + 4] + bias[2][j + 128] + acch[m + 4] + bias[3][j + 128];
      float xn    = accx[m + 8] + bias[2][j + 256];
      float hn    = acch[m + 8] + bias[3][j + 256];
      float rg = 1.f / (1.f + __expf(-pre_r));
      float zg = 1.f / (1.f + __expf(-pre_z));
      float a2 = xn + rg * hn;
      float e2 = __expf(2.f * a2);
      float ng = (e2 - 1.f) / (e2 + 1.f);
      h1s[r][j] = (1.f - zg) * ng + zg * h1s[r][j];
    }
    // no barrier needed here: next readers of h1s are layer1 loops of the next
    // step, separated by >=2 barriers (x-stage, layer0-update).
  }

  __syncthreads();  // head reads all of h1s

  // ---- head fc1: hidden = relu(h1 @ w1^T + b1), units u = g0 and g0+32 ----
  {
    float a0 = 0.f, a1 = 0.f;
    const float* w1r0 = w1 + (size_t)g0 * 128;
    const float* w1r1 = w1 + (size_t)(g0 + 32) * 128;
    for (int k4 = 0; k4 < 32; ++k4) {
      float4 hv  = *(const float4*)&h1s[r][k4 * 4];
      float4 wv0 = *(const float4*)&w1r0[k4 * 4];
      float4 wv1 = *(const float4*)&w1r1[k4 * 4];
      a0 = fmaf(wv0.x, hv.x, fmaf(wv0.y, hv.y, fmaf(wv0.z, hv.z, fmaf(wv0.w, hv.w, a0))));
      a1 = fmaf(wv1.x, hv.x, fmaf(wv1.y, hv.y, fmaf(wv1.z, hv.z, fmaf(wv1.w, hv.w, a1))));
    }
    a0 += b1[g0]; a1 += b1[g0 + 32];
    hid[r][g0]      = a0 > 0.f ? a0 : 0.f;
    hid[r][g0 + 32] = a1 > 0.f ? a1 : 0.f;
  }
  __syncthreads();

  // ---- head fc2: out = hidden @ w2^T + b2 ----
  if (tid < RPB * 11) {
    int rr = tid / 11, c = tid - rr * 11;
    float acc = b2[c];
    for (int k = 0; k < 64; ++k) acc = fmaf(w2[c * 64 + k], hid[rr][k], acc);
    out[(b0 + rr) * 11 + c] = acc;
  }
}

extern "C" void kernel_launch(void* const* d_in, const int* in_sizes, int n_in,
                              void* d_out, int out_size, void* d_ws, size_t ws_size,
                              hipStream_t stream) {
  (void)in_sizes; (void)n_in; (void)out_size; (void)ws_size;
  const float* x    = (const float*)d_in[0];
  const float* wih0 = (const float*)d_in[1];
  const float* whh0 = (const float*)d_in[2];
  const float* bih0 = (const float*)d_in[3];
  const float* bhh0 = (const float*)d_in[4];
  const float* wih1 = (const float*)d_in[5];
  const float* whh1 = (const float*)d_in[6];
  const float* bih1 = (const float*)d_in[7];
  const float* bhh1 = (const float*)d_in[8];
  const float* w1   = (const float*)d_in[9];
  const float* b1   = (const float*)d_in[10];
  const float* w2   = (const float*)d_in[11];
  const float* b2   = (const float*)d_in[12];

  float* ws     = (float*)d_ws;
  float* wih0p  = ws;                 // 384*64  = 24576 floats
  float* whh0p  = ws + 24576;         // 384*128 = 49152
  float* wih1p  = ws + 73728;         // 49152
  float* whh1p  = ws + 122880;        // 49152  (total 688128 bytes)

  hipLaunchKernelGGL(pack_w, dim3(96),  dim3(256), 0, stream, wih0, wih0p, 64, 63);
  hipLaunchKernelGGL(pack_w, dim3(192), dim3(256), 0, stream, whh0, whh0p, 128, 128);
  hipLaunchKernelGGL(pack_w, dim3(192), dim3(256), 0, stream, wih1, wih1p, 128, 128);
  hipLaunchKernelGGL(pack_w, dim3(192), dim3(256), 0, stream, whh1, whh1p, 128, 128);

  hipLaunchKernelGGL(gru_fused, dim3(256), dim3(NTHR), 0, stream,
                     x, wih0p, whh0p, wih1p, whh1p,
                     bih0, bhh0, bih1, bhh1, w1, b1, w2, b2, (float*)d_out);
}

// Round 2
// 5078.173 us; speedup vs baseline: 4.8019x; 4.8019x over previous
//
#include <hip/hip_runtime.h>
#include <hip/hip_bf16.h>

#define Tseq 128
#define HID  128
#define Din  63
#define NCLS 11
#define RPB  16

// ---- swizzled position of hidden element u within a padded row of 140 ----
// breaks the 8s-mod-32 bank collision of 8-float slices (2-way max, free)
__device__ __forceinline__ int hpos(int u) { return u + ((u >> 5) << 2); }
#define HSTR 140

__device__ __forceinline__ float dot4(float4 a, float4 b) {
  return fmaf(a.x, b.x, fmaf(a.y, b.y, fmaf(a.z, b.z, a.w * b.w)));
}

// rotate-reduce within each 16-lane row via DPP ROW_ROR — all 16 lanes get the sum
__device__ __forceinline__ float rowsum16(float v) {
  v += __int_as_float(__builtin_amdgcn_update_dpp(0, __float_as_int(v), 0x121, 0xf, 0xf, true));
  v += __int_as_float(__builtin_amdgcn_update_dpp(0, __float_as_int(v), 0x122, 0xf, 0xf, true));
  v += __int_as_float(__builtin_amdgcn_update_dpp(0, __float_as_int(v), 0x124, 0xf, 0xf, true));
  v += __int_as_float(__builtin_amdgcn_update_dpp(0, __float_as_int(v), 0x128, 0xf, 0xf, true));
  return v;
}

__device__ __forceinline__ float sigm(float p) { return 1.f / (1.f + __expf(-p)); }
__device__ __forceinline__ float tanh_safe(float a) {
  float t = __expf(-2.f * fabsf(a));
  float ng = (1.f - t) / (1.f + t);
  return a < 0.f ? -ng : ng;
}

// ---------------- weight pack kernels ----------------
// L0: dst float4-indexed [j][tid]: j = h*9 + m*3 + p ; thread: ug=t>>4, s=t&15
// gate g = ug + 64h + 128m ; p0: x k=s*4+c (pad>=63) ; p1/p2: h k=s*8+4(p-1)+c
__global__ void pack_l0(const float* __restrict__ wih, const float* __restrict__ whh,
                        float* __restrict__ dst) {
  int idx = blockIdx.x * 256 + threadIdx.x;
  if (idx >= 18 * 1024 * 4) return;
  int c = idx & 3; int tmp = idx >> 2; int t = tmp & 1023; int j = tmp >> 10;
  int s = t & 15, ug = t >> 4;
  int h = j / 9, rem = j % 9, m = rem / 3, p = rem % 3;
  int g = ug + 64 * h + 128 * m;
  float v;
  if (p == 0) { int k = s * 4 + c; v = (k < Din) ? wih[g * Din + k] : 0.f; }
  else        { int k = s * 8 + 4 * (p - 1) + c; v = whh[g * HID + k]; }
  dst[idx] = v;
}
// L1: j = q*12 + m*4 + p ; thread: ug=t>>4 (0..31), s=t&15 ; g = ug+32q+128m
// p0/p1: h0in k = s*8+4(p&1)+c from wih1 ; p2/p3: h1 k from whh1
__global__ void pack_l1(const float* __restrict__ wih, const float* __restrict__ whh,
                        float* __restrict__ dst) {
  int idx = blockIdx.x * 256 + threadIdx.x;
  if (idx >= 48 * 512 * 4) return;
  int c = idx & 3; int tmp = idx >> 2; int t = tmp & 511; int j = tmp >> 9;
  int s = t & 15, ug = t >> 4;
  int q = j / 12, rem = j % 12, m = rem / 4, p = rem % 4;
  int g = ug + 32 * q + 128 * m;
  int k = s * 8 + 4 * (p & 1) + c;
  dst[idx] = (p < 2) ? wih[g * HID + k] : whh[g * HID + k];
}

// ---------------- layer 0 ----------------
__global__ __launch_bounds__(1024, 4) void gru_l0(
    const float* __restrict__ x, const float* __restrict__ wpack,
    const float* __restrict__ bi, const float* __restrict__ bh,
    float* __restrict__ h0chunk, float* __restrict__ h0_state,
    int t0, int tc, int first)
{
  __shared__ float hs[2][RPB][HSTR];
  __shared__ float xs[2][RPB][68];
  __shared__ float bis[384], bhs[384];
  const int tid = threadIdx.x;
  const int s = tid & 15, ug = tid >> 4;  // ug 0..63 -> units ug, ug+64
  const long b0 = (long)blockIdx.x * RPB;

  float4 w[18];
  const float4* wp4 = (const float4*)wpack;
  #pragma unroll
  for (int j = 0; j < 18; ++j) w[j] = wp4[j * 1024 + tid];

  for (int i = tid; i < 384; i += 1024) { bis[i] = bi[i]; bhs[i] = bh[i]; }
  for (int i = tid; i < 2 * RPB * 68; i += 1024) (&xs[0][0][0])[i] = 0.f;
  if (first) {
    for (int i = tid; i < 2 * RPB * HSTR; i += 1024) (&hs[0][0][0])[i] = 0.f;
  } else {
    int f2 = tid * 2; int rr = f2 >> 7; int u2 = f2 & 127;
    float2 v = *(const float2*)&h0_state[(b0 + rr) * HID + u2];
    *(float2*)&hs[0][rr][hpos(u2)] = v;
  }
  // stage x(t0) into buf0
  if (tid < RPB * Din) {
    int rr = tid / Din, k = tid - rr * Din;
    xs[0][rr][k] = x[((b0 + rr) * (long)Tseq + t0) * Din + k];
  }
  __syncthreads();

  int cur = 0;
  for (int tl = 0; tl < tc; ++tl) {
    const int nb = cur ^ 1;
    if (tl + 1 < tc && tid < RPB * Din) {
      int rr = tid / Din, k = tid - rr * Din;
      xs[nb][rr][k] = x[((b0 + rr) * (long)Tseq + (t0 + tl + 1)) * Din + k];
    }
    if (tl > 0) {  // copy state after step tl-1 (in cur) to h0chunk[tl-1]
      int f2 = tid * 2; int rr = f2 >> 7; int u2 = f2 & 127;
      float2 v = *(const float2*)&hs[cur][rr][hpos(u2)];
      *(float2*)&h0chunk[((long)(tl - 1) * 4096 + b0 + rr) * HID + u2] = v;
    }
    float preg[8] = {0, 0, 0, 0, 0, 0, 0, 0};
    for (int r = 0; r < RPB; ++r) {
      float4 xv  = *(const float4*)&xs[cur][r][s * 4];
      float4 h0v = *(const float4*)&hs[cur][r][hpos(s * 8)];
      float4 h1v = *(const float4*)&hs[cur][r][hpos(s * 8) + 4];
      float acc[8];
      acc[0] = dot4(w[0], xv) + dot4(w[1], h0v) + dot4(w[2], h1v);
      acc[1] = dot4(w[3], xv) + dot4(w[4], h0v) + dot4(w[5], h1v);
      acc[2] = dot4(w[6], xv);
      acc[3] = dot4(w[7], h0v) + dot4(w[8], h1v);
      acc[4] = dot4(w[9], xv) + dot4(w[10], h0v) + dot4(w[11], h1v);
      acc[5] = dot4(w[12], xv) + dot4(w[13], h0v) + dot4(w[14], h1v);
      acc[6] = dot4(w[15], xv);
      acc[7] = dot4(w[16], h0v) + dot4(w[17], h1v);
      #pragma unroll
      for (int i = 0; i < 8; ++i) {
        float v = rowsum16(acc[i]);
        if (s == r) preg[i] = v;
      }
    }
    {  // pointwise: my row = s, units ug and ug+64
      const int r = s;
      #pragma unroll
      for (int h = 0; h < 2; ++h) {
        int u = ug + 64 * h;
        float hold = hs[cur][r][hpos(u)];
        float pr = preg[4 * h + 0] + bis[u] + bhs[u];
        float pz = preg[4 * h + 1] + bis[u + 128] + bhs[u + 128];
        float xn = preg[4 * h + 2] + bis[u + 256];
        float hn = preg[4 * h + 3] + bhs[u + 256];
        float rg = sigm(pr), zg = sigm(pz);
        float ng = tanh_safe(xn + rg * hn);
        hs[nb][r][hpos(u)] = (1.f - zg) * ng + zg * hold;
      }
    }
    __syncthreads();
    cur ^= 1;
  }
  {  // final copy: state after step tc-1 -> h0chunk[tc-1] and h0_state
    int f2 = tid * 2; int rr = f2 >> 7; int u2 = f2 & 127;
    float2 v = *(const float2*)&hs[cur][rr][hpos(u2)];
    *(float2*)&h0chunk[((long)(tc - 1) * 4096 + b0 + rr) * HID + u2] = v;
    *(float2*)&h0_state[(b0 + rr) * HID + u2] = v;
  }
}

// ---------------- layer 1 (+ fused head at last chunk) ----------------
__global__ __launch_bounds__(512, 2) void gru_l1(
    const float* __restrict__ wpack,
    const float* __restrict__ bi, const float* __restrict__ bh,
    const float* __restrict__ h0chunk, float* __restrict__ h1_state,
    const float* __restrict__ w1, const float* __restrict__ b1,
    const float* __restrict__ w2, const float* __restrict__ b2,
    float* __restrict__ out, int tc, int first, int last)
{
  __shared__ float hs[2][RPB][HSTR];   // h1 state
  __shared__ float gs[2][RPB][HSTR];   // staged h0 input
  __shared__ float bis[384], bhs[384];
  __shared__ float w1s[64][132];
  __shared__ float hid[RPB][68];
  const int tid = threadIdx.x;
  const int s = tid & 15, ug = tid >> 4;  // ug 0..31 -> units ug+32q
  const long b0 = (long)blockIdx.x * RPB;

  float4 w[48];
  const float4* wp4 = (const float4*)wpack;
  #pragma unroll
  for (int j = 0; j < 48; ++j) w[j] = wp4[j * 512 + tid];

  for (int i = tid; i < 384; i += 512) { bis[i] = bi[i]; bhs[i] = bh[i]; }
  if (first) {
    for (int i = tid; i < 2 * RPB * HSTR; i += 512) (&hs[0][0][0])[i] = 0.f;
  } else {
    int f4 = tid * 4; int rr = f4 >> 7; int u4 = f4 & 127;
    float4 v = *(const float4*)&h1_state[(b0 + rr) * HID + u4];
    *(float4*)&hs[0][rr][hpos(u4)] = v;
  }
  {  // stage h0chunk[0] into gs[0]
    int f4 = tid * 4; int rr = f4 >> 7; int u4 = f4 & 127;
    float4 v = *(const float4*)&h0chunk[((long)0 * 4096 + b0 + rr) * HID + u4];
    *(float4*)&gs[0][rr][hpos(u4)] = v;
  }
  __syncthreads();

  int cur = 0;
  for (int tl = 0; tl < tc; ++tl) {
    const int nb = cur ^ 1;
    if (tl + 1 < tc) {
      int f4 = tid * 4; int rr = f4 >> 7; int u4 = f4 & 127;
      float4 v = *(const float4*)&h0chunk[((long)(tl + 1) * 4096 + b0 + rr) * HID + u4];
      *(float4*)&gs[nb][rr][hpos(u4)] = v;
    }
    float preg[16];
    #pragma unroll
    for (int i = 0; i < 16; ++i) preg[i] = 0.f;
    for (int r = 0; r < RPB; ++r) {
      float acc[16];
      #pragma unroll
      for (int i = 0; i < 16; ++i) acc[i] = 0.f;
      {  // batch 1: h0-input part
        float4 g0 = *(const float4*)&gs[cur][r][hpos(s * 8)];
        float4 g1 = *(const float4*)&gs[cur][r][hpos(s * 8) + 4];
        #pragma unroll
        for (int q = 0; q < 4; ++q) {
          acc[q * 4 + 0] += dot4(w[q * 12 + 0], g0) + dot4(w[q * 12 + 1], g1);
          acc[q * 4 + 1] += dot4(w[q * 12 + 4], g0) + dot4(w[q * 12 + 5], g1);
          acc[q * 4 + 2] += dot4(w[q * 12 + 8], g0) + dot4(w[q * 12 + 9], g1);
        }
      }
      {  // batch 2: h1 recurrent part
        float4 h0v = *(const float4*)&hs[cur][r][hpos(s * 8)];
        float4 h1v = *(const float4*)&hs[cur][r][hpos(s * 8) + 4];
        #pragma unroll
        for (int q = 0; q < 4; ++q) {
          acc[q * 4 + 0] += dot4(w[q * 12 + 2], h0v) + dot4(w[q * 12 + 3], h1v);
          acc[q * 4 + 1] += dot4(w[q * 12 + 6], h0v) + dot4(w[q * 12 + 7], h1v);
          acc[q * 4 + 3] += dot4(w[q * 12 + 10], h0v) + dot4(w[q * 12 + 11], h1v);
        }
      }
      #pragma unroll
      for (int i = 0; i < 16; ++i) {
        float v = rowsum16(acc[i]);
        if (s == r) preg[i] = v;
      }
    }
    {  // pointwise: my row = s, units ug + 32q
      const int r = s;
      #pragma unroll
      for (int q = 0; q < 4; ++q) {
        int u = ug + 32 * q;
        float hold = hs[cur][r][hpos(u)];
        float pr = preg[4 * q + 0] + bis[u] + bhs[u];
        float pz = preg[4 * q + 1] + bis[u + 128] + bhs[u + 128];
        float xn = preg[4 * q + 2] + bis[u + 256];
        float hn = preg[4 * q + 3] + bhs[u + 256];
        float rg = sigm(pr), zg = sigm(pz);
        float ng = tanh_safe(xn + rg * hn);
        hs[nb][r][hpos(u)] = (1.f - zg) * ng + zg * hold;
      }
    }
    __syncthreads();
    cur ^= 1;
  }
  {  // persist h1 state
    int f4 = tid * 4; int rr = f4 >> 7; int u4 = f4 & 127;
    float4 v = *(const float4*)&hs[cur][rr][hpos(u4)];
    *(float4*)&h1_state[(b0 + rr) * HID + u4] = v;
  }
  if (!last) return;

  // ---------------- head ----------------
  for (int i = tid; i < 64 * HID; i += 512) w1s[i >> 7][i & 127] = w1[i];
  __syncthreads();
  {  // fc1: r = tid&15, units fu and fu+32
    int r = tid & 15, fu = tid >> 4;
    float a0 = 0.f, a1 = 0.f;
    for (int k4 = 0; k4 < 32; ++k4) {
      float4 hv = *(const float4*)&hs[cur][r][hpos(k4 * 4)];
      float4 wa = *(const float4*)&w1s[fu][k4 * 4];
      float4 wb = *(const float4*)&w1s[fu + 32][k4 * 4];
      a0 += dot4(wa, hv);
      a1 += dot4(wb, hv);
    }
    a0 += b1[fu]; a1 += b1[fu + 32];
    hid[r][fu]      = a0 > 0.f ? a0 : 0.f;
    hid[r][fu + 32] = a1 > 0.f ? a1 : 0.f;
  }
  __syncthreads();
  if (tid < RPB * NCLS) {
    int rr = tid / NCLS, c = tid - rr * NCLS;
    float acc = b2[c];
    for (int k = 0; k < 64; ++k) acc = fmaf(w2[c * 64 + k], hid[rr][k], acc);
    out[(b0 + rr) * NCLS + c] = acc;
  }
}

extern "C" void kernel_launch(void* const* d_in, const int* in_sizes, int n_in,
                              void* d_out, int out_size, void* d_ws, size_t ws_size,
                              hipStream_t stream) {
  (void)in_sizes; (void)n_in; (void)out_size;
  const float* x    = (const float*)d_in[0];
  const float* wih0 = (const float*)d_in[1];
  const float* whh0 = (const float*)d_in[2];
  const float* bih0 = (const float*)d_in[3];
  const float* bhh0 = (const float*)d_in[4];
  const float* wih1 = (const float*)d_in[5];
  const float* whh1 = (const float*)d_in[6];
  const float* bih1 = (const float*)d_in[7];
  const float* bhh1 = (const float*)d_in[8];
  const float* w1   = (const float*)d_in[9];
  const float* b1   = (const float*)d_in[10];
  const float* w2   = (const float*)d_in[11];
  const float* b2   = (const float*)d_in[12];

  float* ws   = (float*)d_ws;
  float* wpL0 = ws;             // 73728 floats
  float* wpL1 = ws + 73728;     // 98304
  float* h0st = ws + 172032;    // 524288
  float* h1st = ws + 696320;    // 524288
  float* h0ch = ws + 1220608;   // Tc * 524288

  long avail = (long)(ws_size / 4) - 1220608L;
  long q = avail / 524288L;
  int Tc = q > 128 ? 128 : (int)q;
  if (Tc < 1) return;  // ws too small — fail loudly

  hipLaunchKernelGGL(pack_l0, dim3((73728 + 255) / 256), dim3(256), 0, stream, wih0, whh0, wpL0);
  hipLaunchKernelGGL(pack_l1, dim3((98304 + 255) / 256), dim3(256), 0, stream, wih1, whh1, wpL1);

  for (int t0 = 0; t0 < Tseq; t0 += Tc) {
    int tc = (Tseq - t0) < Tc ? (Tseq - t0) : Tc;
    hipLaunchKernelGGL(gru_l0, dim3(256), dim3(1024), 0, stream,
                       x, wpL0, bih0, bhh0, h0ch, h0st, t0, tc, (int)(t0 == 0));
    hipLaunchKernelGGL(gru_l1, dim3(256), dim3(512), 0, stream,
                       wpL1, bih1, bhh1, h0ch, h1st, w1, b1, w2, b2,
                       (float*)d_out, tc, (int)(t0 == 0), (int)(t0 + tc == Tseq));
  }
}

// Round 3
// 945.032 us; speedup vs baseline: 25.8033x; 5.3735x over previous
//
#include <hip/hip_runtime.h>
#include <hip/hip_bf16.h>

typedef __attribute__((ext_vector_type(8))) short s8v;   // 8 bf16 = 4 VGPR
typedef __attribute__((ext_vector_type(4))) float f4v;   // MFMA acc

#define MF(A, B, C) C = __builtin_amdgcn_mfma_f32_16x16x32_bf16((A), (B), (C), 0, 0, 0)

__device__ __forceinline__ ushort f2bf(float f) {
  unsigned u = __float_as_uint(f);
  u += 0x7FFF + ((u >> 16) & 1);        // RNE (finite inputs only)
  return (ushort)(u >> 16);
}
__device__ __forceinline__ float bf2f(ushort h) {
  return __uint_as_float(((unsigned)h) << 16);
}
__device__ __forceinline__ float sigm(float p) { return 1.f / (1.f + __expf(-p)); }
__device__ __forceinline__ float tanh_safe(float a) {
  float t = __expf(-2.f * fabsf(a));
  float ng = (1.f - t) / (1.f + t);
  return a < 0.f ? -ng : ng;
}
__device__ __forceinline__ float dot4(float4 a, float4 b) {
  return fmaf(a.x, b.x, fmaf(a.y, b.y, fmaf(a.z, b.z, a.w * b.w)));
}

// ---------- pre-pass: split x (fp32 [4096*128][63]) into bf16 hi/lo, pad K to 64 ----------
__global__ void conv_x(const float* __restrict__ x, ushort* __restrict__ xhi,
                       ushort* __restrict__ xlo, int total) {
  int idx = blockIdx.x * 256 + threadIdx.x;
  if (idx >= total) return;                    // total = 4096*128*16 (4 elems each)
  int k4 = (idx & 15) * 4;
  long bt = idx >> 4;
  #pragma unroll
  for (int j = 0; j < 4; ++j) {
    int k = k4 + j;
    float v = (k < 63) ? x[bt * 63 + k] : 0.f;
    ushort hi = f2bf(v);
    xhi[bt * 64 + k] = hi;
    xlo[bt * 64 + k] = f2bf(v - bf2f(hi));
  }
}

// ---------- pre-pass: pack W [384][Kreal] into per-lane B-frag streams (hi/lo bf16) ----------
// frag_id = (nt*KT + kt)*2 + hl ; elem = frag_id*512 + l*8 + i
// B-frag lane l, elem i supplies B[k = kt*32 + (l>>4)*8 + i][n = nt*16 + (l&15)] = W[n][k]
__global__ void pack_fr(const float* __restrict__ src, ushort* __restrict__ dst,
                        int Kreal, int KT, int total) {
  int idx = blockIdx.x * 256 + threadIdx.x;
  if (idx >= total) return;
  int i = idx & 7, l = (idx >> 3) & 63, hl = (idx >> 9) & 1;
  int rest = idx >> 10;                       // nt*KT + kt
  int kt = rest % KT, nt = rest / KT;
  int g = nt * 16 + (l & 15);
  int k = kt * 32 + (l >> 4) * 8 + i;
  float v = (k < Kreal) ? src[g * Kreal + k] : 0.f;
  ushort hi = f2bf(v);
  dst[idx] = hl ? f2bf(v - bf2f(hi)) : hi;
}

// ---------- layer 0 recurrent (ih fused): 16 rows/block, 8 waves ----------
__global__ __launch_bounds__(512, 2) void rec_l0(
    const ushort* __restrict__ xhi, const ushort* __restrict__ xlo,
    const ushort* __restrict__ fih, const ushort* __restrict__ fhh,
    const float* __restrict__ bih, const float* __restrict__ bhh,
    ushort* __restrict__ s_hi, ushort* __restrict__ s_lo,
    ushort* __restrict__ c_hi, ushort* __restrict__ c_lo,
    int t0, int tc, int first)
{
  __shared__ __align__(16) ushort hhi[16 * 128], hlo[16 * 128];   // swizzled h state pair
  __shared__ __align__(16) float pr_[16 * 132], pz_[16 * 132], pnx_[16 * 132], pnh_[16 * 132];
  __shared__ __align__(16) float bb[512];
  const int tid = threadIdx.x;
  const int l = tid & 63, w = tid >> 6;
  const int lr = l & 15, lg = l >> 4;            // A-frag row / k-group
  const int row = tid & 15, u0 = (tid >> 4) * 4; // pointwise ownership
  const long b0 = (long)blockIdx.x * 16;

  if (tid < 128) {
    bb[tid]       = bih[tid] + bhh[tid];
    bb[128 + tid] = bih[128 + tid] + bhh[128 + tid];
    bb[256 + tid] = bih[256 + tid];
    bb[384 + tid] = bhh[256 + tid];
  }
  const int hoff = row * 256 + ((u0 * 2) ^ ((row & 7) << 4));  // my 4 units (bytes)
  if (first) {
    *(ushort4*)((char*)hhi + hoff) = make_ushort4(0, 0, 0, 0);
    *(ushort4*)((char*)hlo + hoff) = make_ushort4(0, 0, 0, 0);
  } else {
    *(ushort4*)((char*)hhi + hoff) = *(const ushort4*)&c_hi[(b0 + row) * 128 + u0];
    *(ushort4*)((char*)hlo + hoff) = *(const ushort4*)&c_lo[(b0 + row) * 128 + u0];
  }
  // parked B-frags: gate gi -> nt = w + 8*gi
  s8v Bih[12];   // [(gi*2+kt)*2+hl]
  s8v Bhh[24];   // [(gi*4+kt)*2+hl]
  #pragma unroll
  for (int gi = 0; gi < 3; ++gi) {
    int nt = w + 8 * gi;
    #pragma unroll
    for (int kt = 0; kt < 2; ++kt)
      #pragma unroll
      for (int hl = 0; hl < 2; ++hl)
        Bih[(gi * 2 + kt) * 2 + hl] = *(const s8v*)&fih[((long)((nt * 2 + kt) * 2 + hl)) * 512 + l * 8];
    #pragma unroll
    for (int kt = 0; kt < 4; ++kt)
      #pragma unroll
      for (int hl = 0; hl < 2; ++hl)
        Bhh[(gi * 4 + kt) * 2 + hl] = *(const s8v*)&fhh[((long)((nt * 4 + kt) * 2 + hl)) * 512 + l * 8];
  }
  __syncthreads();

  for (int tl = 0; tl < tc; ++tl) {
    const int t = t0 + tl;
    // x A-frags (global; issued early, covered by hh MFMAs)
    s8v Axh[2], Axl[2];
    {
      long xo = ((b0 + lr) * 128 + t) * 64 + lg * 8;
      Axh[0] = *(const s8v*)&xhi[xo];       Axh[1] = *(const s8v*)&xhi[xo + 32];
      Axl[0] = *(const s8v*)&xlo[xo];       Axl[1] = *(const s8v*)&xlo[xo + 32];
    }
    // h A-frags (LDS, swizzled)
    s8v Ahh[4], Ahl[4];
    #pragma unroll
    for (int kt = 0; kt < 4; ++kt) {
      int ba = lr * 256 + ((kt * 64 + lg * 16) ^ ((lr & 7) << 4));
      Ahh[kt] = *(const s8v*)((const char*)hhi + ba);
      Ahl[kt] = *(const s8v*)((const char*)hlo + ba);
    }
    f4v ar = {0.f, 0.f, 0.f, 0.f}, az = ar, anx = ar, anh = ar;
    #pragma unroll
    for (int kt = 0; kt < 4; ++kt) {     // hh: r, z, nh (3 split-terms each)
      MF(Ahh[kt], Bhh[(0 * 4 + kt) * 2 + 0], ar);
      MF(Ahl[kt], Bhh[(0 * 4 + kt) * 2 + 0], ar);
      MF(Ahh[kt], Bhh[(0 * 4 + kt) * 2 + 1], ar);
      MF(Ahh[kt], Bhh[(1 * 4 + kt) * 2 + 0], az);
      MF(Ahl[kt], Bhh[(1 * 4 + kt) * 2 + 0], az);
      MF(Ahh[kt], Bhh[(1 * 4 + kt) * 2 + 1], az);
      MF(Ahh[kt], Bhh[(2 * 4 + kt) * 2 + 0], anh);
      MF(Ahl[kt], Bhh[(2 * 4 + kt) * 2 + 0], anh);
      MF(Ahh[kt], Bhh[(2 * 4 + kt) * 2 + 1], anh);
    }
    #pragma unroll
    for (int kt = 0; kt < 2; ++kt) {     // ih: r, z, nx
      MF(Axh[kt], Bih[(0 * 2 + kt) * 2 + 0], ar);
      MF(Axl[kt], Bih[(0 * 2 + kt) * 2 + 0], ar);
      MF(Axh[kt], Bih[(0 * 2 + kt) * 2 + 1], ar);
      MF(Axh[kt], Bih[(1 * 2 + kt) * 2 + 0], az);
      MF(Axl[kt], Bih[(1 * 2 + kt) * 2 + 0], az);
      MF(Axh[kt], Bih[(1 * 2 + kt) * 2 + 1], az);
      MF(Axh[kt], Bih[(2 * 2 + kt) * 2 + 0], anx);
      MF(Axl[kt], Bih[(2 * 2 + kt) * 2 + 0], anx);
      MF(Axh[kt], Bih[(2 * 2 + kt) * 2 + 1], anx);
    }
    {  // dump C: lane l holds rows lg*4+d, col l&15 of tile -> unit u = w*16 + (l&15)
      int du = w * 16 + lr;
      #pragma unroll
      for (int d = 0; d < 4; ++d) {
        int rw = lg * 4 + d;
        pr_[rw * 132 + du] = ar[d];
        pz_[rw * 132 + du] = az[d];
        pnx_[rw * 132 + du] = anx[d];
        pnh_[rw * 132 + du] = anh[d];
      }
    }
    __syncthreads();
    {  // pointwise: thread owns (row, u0..u0+3)
      f4v vr  = *(const f4v*)&pr_[row * 132 + u0];
      f4v vz  = *(const f4v*)&pz_[row * 132 + u0];
      f4v vnx = *(const f4v*)&pnx_[row * 132 + u0];
      f4v vnh = *(const f4v*)&pnh_[row * 132 + u0];
      f4v br4 = *(const f4v*)&bb[u0];
      f4v bz4 = *(const f4v*)&bb[128 + u0];
      f4v bx4 = *(const f4v*)&bb[256 + u0];
      f4v bh4 = *(const f4v*)&bb[384 + u0];
      ushort4 oh = *(const ushort4*)((const char*)hhi + hoff);
      ushort4 ol = *(const ushort4*)((const char*)hlo + hoff);
      ushort nh_[4], nl_[4];
      const ushort* ohp = (const ushort*)&oh;
      const ushort* olp = (const ushort*)&ol;
      #pragma unroll
      for (int j = 0; j < 4; ++j) {
        float hold = bf2f(ohp[j]) + bf2f(olp[j]);
        float rg = sigm(vr[j] + br4[j]);
        float zg = sigm(vz[j] + bz4[j]);
        float ng = tanh_safe(vnx[j] + bx4[j] + rg * (vnh[j] + bh4[j]));
        float hn = (1.f - zg) * ng + zg * hold;
        ushort hb = f2bf(hn);
        nh_[j] = hb;
        nl_[j] = f2bf(hn - bf2f(hb));
      }
      ushort4 wh = make_ushort4(nh_[0], nh_[1], nh_[2], nh_[3]);
      ushort4 wl = make_ushort4(nl_[0], nl_[1], nl_[2], nl_[3]);
      *(ushort4*)((char*)hhi + hoff) = wh;
      *(ushort4*)((char*)hlo + hoff) = wl;
      long so = ((long)tl * 4096 + b0 + row) * 128 + u0;
      *(ushort4*)&s_hi[so] = wh;
      *(ushort4*)&s_lo[so] = wl;
    }
    __syncthreads();
  }
  *(ushort4*)&c_hi[(b0 + row) * 128 + u0] = *(const ushort4*)((const char*)hhi + hoff);
  *(ushort4*)&c_lo[(b0 + row) * 128 + u0] = *(const ushort4*)((const char*)hlo + hoff);
}

// ---------- layer 1 recurrent (ih from h0 stream) ----------
__global__ __launch_bounds__(512, 1) void rec_l1(
    const ushort* __restrict__ s_hi, const ushort* __restrict__ s_lo,
    const ushort* __restrict__ fih, const ushort* __restrict__ fhh,
    const float* __restrict__ bih, const float* __restrict__ bhh,
    ushort* __restrict__ c_hi, ushort* __restrict__ c_lo,
    float* __restrict__ h1f, int tc, int first, int last)
{
  __shared__ __align__(16) ushort hhi[16 * 128], hlo[16 * 128];
  __shared__ __align__(16) float pr_[16 * 132], pz_[16 * 132], pnx_[16 * 132], pnh_[16 * 132];
  __shared__ __align__(16) float bb[512];
  const int tid = threadIdx.x;
  const int l = tid & 63, w = tid >> 6;
  const int lr = l & 15, lg = l >> 4;
  const int row = tid & 15, u0 = (tid >> 4) * 4;
  const long b0 = (long)blockIdx.x * 16;

  if (tid < 128) {
    bb[tid]       = bih[tid] + bhh[tid];
    bb[128 + tid] = bih[128 + tid] + bhh[128 + tid];
    bb[256 + tid] = bih[256 + tid];
    bb[384 + tid] = bhh[256 + tid];
  }
  const int hoff = row * 256 + ((u0 * 2) ^ ((row & 7) << 4));
  if (first) {
    *(ushort4*)((char*)hhi + hoff) = make_ushort4(0, 0, 0, 0);
    *(ushort4*)((char*)hlo + hoff) = make_ushort4(0, 0, 0, 0);
  } else {
    *(ushort4*)((char*)hhi + hoff) = *(const ushort4*)&c_hi[(b0 + row) * 128 + u0];
    *(ushort4*)((char*)hlo + hoff) = *(const ushort4*)&c_lo[(b0 + row) * 128 + u0];
  }
  s8v Bih[24];   // [(gi*4+kt)*2+hl]
  s8v Bhh[24];
  #pragma unroll
  for (int gi = 0; gi < 3; ++gi) {
    int nt = w + 8 * gi;
    #pragma unroll
    for (int kt = 0; kt < 4; ++kt)
      #pragma unroll
      for (int hl = 0; hl < 2; ++hl) {
        Bih[(gi * 4 + kt) * 2 + hl] = *(const s8v*)&fih[((long)((nt * 4 + kt) * 2 + hl)) * 512 + l * 8];
        Bhh[(gi * 4 + kt) * 2 + hl] = *(const s8v*)&fhh[((long)((nt * 4 + kt) * 2 + hl)) * 512 + l * 8];
      }
  }
  __syncthreads();

  for (int tl = 0; tl < tc; ++tl) {
    // h0-input A-frags (global stream)
    s8v Agh[4], Agl[4];
    {
      long go = ((long)tl * 4096 + b0 + lr) * 128 + lg * 8;
      #pragma unroll
      for (int kt = 0; kt < 4; ++kt) {
        Agh[kt] = *(const s8v*)&s_hi[go + kt * 32];
        Agl[kt] = *(const s8v*)&s_lo[go + kt * 32];
      }
    }
    // h1 A-frags (LDS)
    s8v Ahh[4], Ahl[4];
    #pragma unroll
    for (int kt = 0; kt < 4; ++kt) {
      int ba = lr * 256 + ((kt * 64 + lg * 16) ^ ((lr & 7) << 4));
      Ahh[kt] = *(const s8v*)((const char*)hhi + ba);
      Ahl[kt] = *(const s8v*)((const char*)hlo + ba);
    }
    f4v ar = {0.f, 0.f, 0.f, 0.f}, az = ar, anx = ar, anh = ar;
    #pragma unroll
    for (int kt = 0; kt < 4; ++kt) {
      // hh (h1 recurrent): r, z, nh
      MF(Ahh[kt], Bhh[(0 * 4 + kt) * 2 + 0], ar);
      MF(Ahl[kt], Bhh[(0 * 4 + kt) * 2 + 0], ar);
      MF(Ahh[kt], Bhh[(0 * 4 + kt) * 2 + 1], ar);
      MF(Ahh[kt], Bhh[(1 * 4 + kt) * 2 + 0], az);
      MF(Ahl[kt], Bhh[(1 * 4 + kt) * 2 + 0], az);
      MF(Ahh[kt], Bhh[(1 * 4 + kt) * 2 + 1], az);
      MF(Ahh[kt], Bhh[(2 * 4 + kt) * 2 + 0], anh);
      MF(Ahl[kt], Bhh[(2 * 4 + kt) * 2 + 0], anh);
      MF(Ahh[kt], Bhh[(2 * 4 + kt) * 2 + 1], anh);
      // ih (h0 input): r, z, nx
      MF(Agh[kt], Bih[(0 * 4 + kt) * 2 + 0], ar);
      MF(Agl[kt], Bih[(0 * 4 + kt) * 2 + 0], ar);
      MF(Agh[kt], Bih[(0 * 4 + kt) * 2 + 1], ar);
      MF(Agh[kt], Bih[(1 * 4 + kt) * 2 + 0], az);
      MF(Agl[kt], Bih[(1 * 4 + kt) * 2 + 0], az);
      MF(Agh[kt], Bih[(1 * 4 + kt) * 2 + 1], az);
      MF(Agh[kt], Bih[(2 * 4 + kt) * 2 + 0], anx);
      MF(Agl[kt], Bih[(2 * 4 + kt) * 2 + 0], anx);
      MF(Agh[kt], Bih[(2 * 4 + kt) * 2 + 1], anx);
    }
    {
      int du = w * 16 + lr;
      #pragma unroll
      for (int d = 0; d < 4; ++d) {
        int rw = lg * 4 + d;
        pr_[rw * 132 + du] = ar[d];
        pz_[rw * 132 + du] = az[d];
        pnx_[rw * 132 + du] = anx[d];
        pnh_[rw * 132 + du] = anh[d];
      }
    }
    __syncthreads();
    {
      f4v vr  = *(const f4v*)&pr_[row * 132 + u0];
      f4v vz  = *(const f4v*)&pz_[row * 132 + u0];
      f4v vnx = *(const f4v*)&pnx_[row * 132 + u0];
      f4v vnh = *(const f4v*)&pnh_[row * 132 + u0];
      f4v br4 = *(const f4v*)&bb[u0];
      f4v bz4 = *(const f4v*)&bb[128 + u0];
      f4v bx4 = *(const f4v*)&bb[256 + u0];
      f4v bh4 = *(const f4v*)&bb[384 + u0];
      ushort4 oh = *(const ushort4*)((const char*)hhi + hoff);
      ushort4 ol = *(const ushort4*)((const char*)hlo + hoff);
      ushort nh_[4], nl_[4];
      const ushort* ohp = (const ushort*)&oh;
      const ushort* olp = (const ushort*)&ol;
      #pragma unroll
      for (int j = 0; j < 4; ++j) {
        float hold = bf2f(ohp[j]) + bf2f(olp[j]);
        float rg = sigm(vr[j] + br4[j]);
        float zg = sigm(vz[j] + bz4[j]);
        float ng = tanh_safe(vnx[j] + bx4[j] + rg * (vnh[j] + bh4[j]));
        float hn = (1.f - zg) * ng + zg * hold;
        ushort hb = f2bf(hn);
        nh_[j] = hb;
        nl_[j] = f2bf(hn - bf2f(hb));
      }
      *(ushort4*)((char*)hhi + hoff) = make_ushort4(nh_[0], nh_[1], nh_[2], nh_[3]);
      *(ushort4*)((char*)hlo + hoff) = make_ushort4(nl_[0], nl_[1], nl_[2], nl_[3]);
    }
    __syncthreads();
  }
  {
    ushort4 fh = *(const ushort4*)((const char*)hhi + hoff);
    ushort4 fl = *(const ushort4*)((const char*)hlo + hoff);
    *(ushort4*)&c_hi[(b0 + row) * 128 + u0] = fh;
    *(ushort4*)&c_lo[(b0 + row) * 128 + u0] = fl;
    if (last) {
      const ushort* fhp = (const ushort*)&fh;
      const ushort* flp = (const ushort*)&fl;
      float4 o;
      o.x = bf2f(fhp[0]) + bf2f(flp[0]);
      o.y = bf2f(fhp[1]) + bf2f(flp[1]);
      o.z = bf2f(fhp[2]) + bf2f(flp[2]);
      o.w = bf2f(fhp[3]) + bf2f(flp[3]);
      *(float4*)&h1f[(b0 + row) * 128 + u0] = o;
    }
  }
}

// ---------- head: relu(h1 @ w1^T + b1) @ w2^T + b2 ----------
__global__ __launch_bounds__(512) void head_k(
    const float* __restrict__ h1f, const float* __restrict__ w1,
    const float* __restrict__ b1, const float* __restrict__ w2,
    const float* __restrict__ b2, float* __restrict__ out)
{
  __shared__ float hrow[16][132];
  __shared__ float w1s[64][132];
  __shared__ float hid[16][68];
  const int tid = threadIdx.x;
  const long b0 = (long)blockIdx.x * 16;
  for (int i = tid; i < 64 * 128; i += 512) w1s[i >> 7][i & 127] = w1[i];
  {
    int rr = tid >> 5, k4 = (tid & 31) * 4;
    *(float4*)&hrow[rr][k4] = *(const float4*)&h1f[(b0 + rr) * 128 + k4];
  }
  __syncthreads();
  {
    int r = tid & 15, fu = tid >> 4;
    float a0 = 0.f, a1 = 0.f;
    for (int k4 = 0; k4 < 32; ++k4) {
      float4 hv = *(const float4*)&hrow[r][k4 * 4];
      float4 wa = *(const float4*)&w1s[fu][k4 * 4];
      float4 wb = *(const float4*)&w1s[fu + 32][k4 * 4];
      a0 += dot4(wa, hv);
      a1 += dot4(wb, hv);
    }
    a0 += b1[fu]; a1 += b1[fu + 32];
    hid[r][fu]      = fmaxf(a0, 0.f);
    hid[r][fu + 32] = fmaxf(a1, 0.f);
  }
  __syncthreads();
  if (tid < 176) {
    int rr = tid / 11, c = tid - rr * 11;
    float acc = b2[c];
    for (int k = 0; k < 64; ++k) acc = fmaf(w2[c * 64 + k], hid[rr][k], acc);
    out[(b0 + rr) * 11 + c] = acc;
  }
}

extern "C" void kernel_launch(void* const* d_in, const int* in_sizes, int n_in,
                              void* d_out, int out_size, void* d_ws, size_t ws_size,
                              hipStream_t stream) {
  (void)in_sizes; (void)n_in; (void)out_size;
  const float* x    = (const float*)d_in[0];
  const float* wih0 = (const float*)d_in[1];
  const float* whh0 = (const float*)d_in[2];
  const float* bih0 = (const float*)d_in[3];
  const float* bhh0 = (const float*)d_in[4];
  const float* wih1 = (const float*)d_in[5];
  const float* whh1 = (const float*)d_in[6];
  const float* bih1 = (const float*)d_in[7];
  const float* bhh1 = (const float*)d_in[8];
  const float* w1   = (const float*)d_in[9];
  const float* b1   = (const float*)d_in[10];
  const float* w2   = (const float*)d_in[11];
  const float* b2   = (const float*)d_in[12];

  char* wsb = (char*)d_ws;
  size_t o = 0;
  ushort* fih0 = (ushort*)(wsb + o); o += 98304;      // 24nt*2kt*2hl*1KB
  ushort* fhh0 = (ushort*)(wsb + o); o += 196608;
  ushort* fih1 = (ushort*)(wsb + o); o += 196608;
  ushort* fhh1 = (ushort*)(wsb + o); o += 196608;
  ushort* xhi  = (ushort*)(wsb + o); o += 67108864ULL;
  ushort* xlo  = (ushort*)(wsb + o); o += 67108864ULL;
  ushort* hc0h = (ushort*)(wsb + o); o += 1048576;
  ushort* hc0l = (ushort*)(wsb + o); o += 1048576;
  ushort* hc1h = (ushort*)(wsb + o); o += 1048576;
  ushort* hc1l = (ushort*)(wsb + o); o += 1048576;
  float*  h1f  = (float*)(wsb + o);  o += 2097152;

  long rem = (long)ws_size - (long)o;
  long tcmax = rem / (2 * 1048576L);
  int Tc = tcmax > 128 ? 128 : (int)tcmax;
  if (Tc < 1) return;  // ws too small
  ushort* sh = (ushort*)(wsb + o);
  ushort* sl = sh + (long)Tc * 524288;

  hipLaunchKernelGGL(conv_x, dim3(32768), dim3(256), 0, stream, x, xhi, xlo, 8388608);
  hipLaunchKernelGGL(pack_fr, dim3(192), dim3(256), 0, stream, wih0, fih0, 63, 2, 49152);
  hipLaunchKernelGGL(pack_fr, dim3(384), dim3(256), 0, stream, whh0, fhh0, 128, 4, 98304);
  hipLaunchKernelGGL(pack_fr, dim3(384), dim3(256), 0, stream, wih1, fih1, 128, 4, 98304);
  hipLaunchKernelGGL(pack_fr, dim3(384), dim3(256), 0, stream, whh1, fhh1, 128, 4, 98304);

  for (int t0 = 0; t0 < 128; t0 += Tc) {
    int tc = (128 - t0) < Tc ? (128 - t0) : Tc;
    hipLaunchKernelGGL(rec_l0, dim3(256), dim3(512), 0, stream,
                       xhi, xlo, fih0, fhh0, bih0, bhh0, sh, sl, hc0h, hc0l,
                       t0, tc, (int)(t0 == 0));
    hipLaunchKernelGGL(rec_l1, dim3(256), dim3(512), 0, stream,
                       sh, sl, fih1, fhh1, bih1, bhh1, hc1h, hc1l, h1f,
                       tc, (int)(t0 == 0), (int)(t0 + tc == 128));
  }
  hipLaunchKernelGGL(head_k, dim3(256), dim3(512), 0, stream,
                     h1f, w1, b1, w2, b2, (float*)d_out);
}